// Round 7
// baseline (239.476 us; speedup 1.0000x reference)
//
#include <hip/hip_runtime.h>

// RetinaNet matcher: gt_boxes [B=8, G=64, 4] f32, anchors [A=120000, 4] f32.
// Outputs (concat in d_out, f32): matched_idxs [B,A] (as float), matched_vals [B,A].
//
// Numerics (bit-exact vs np, verified R5/R6 absmax 0.0): opaque() barriers on
// every mul result leave no legal FMA-contraction site -> every op is one
// deterministic IEEE instruction. argmax tie-break = first g (strict >).
// IoU >= 0 -> per-gt max reduces bit-exactly via uint atomicMax.
//
// R7: both passes are VALU-issue bound at ~25 ops/IoU, ~10 of which are the
// correctly-rounded f32 divide. ~90% of pairs have intersection exactly 0.
// Counting-sort anchors into a 16x16 spatial grid (perm only, gather via
// perm[]) so each wave's 64 anchors are spatially coherent; then a wave-
// uniform `if (__ballot(inter > 0))` skips the area/denom/div tail for the
// vast majority of (wave, g) iterations. Skipped pairs have q == +0.0 exactly
// (same as np); q==hg in skip path <=> hg bits == 0, checked scalar-cheap.
// Outputs written to original indices via perm -> sort order (non-stable,
// atomic-racy) cannot affect output bits; hpg max is order-free.
// Fallback: if ws_size too small, perm = nullptr (identity order) -> correct.

static constexpr int G = 64;
static constexpr int NCELL = 256;   // 16 x 16 grid of 50px cells

__device__ __forceinline__ float opaque(float x) {
    asm volatile("" : "+v"(x));  // no-op; blocks FMA contraction across x
    return x;
}

__device__ __forceinline__ float box_area(float x1, float y1, float x2, float y2) {
    return opaque(__fmul_rn(__fsub_rn(x2, x1), __fsub_rn(y2, y1)));
}

__device__ __forceinline__ float inter_area(float gx1, float gy1, float gx2, float gy2,
                                            float ax1, float ay1, float ax2, float ay2) {
    float ltx = fmaxf(gx1, ax1);
    float lty = fmaxf(gy1, ay1);
    float rbx = fminf(gx2, ax2);
    float rby = fminf(gy2, ay2);
    float w = fmaxf(__fsub_rn(rbx, ltx), 0.0f);
    float h = fmaxf(__fsub_rn(rby, lty), 0.0f);
    return opaque(__fmul_rn(w, h));
}

__device__ __forceinline__ float iou_from_inter(float inter, float garea, float aarea) {
    float denom = __fsub_rn(__fadd_rn(garea, aarea), inter);  // no fusable mul feeds this
    return __fdiv_rn(inter, denom);
}

// ---- spatial binning (perf only; outputs never depend on bin order) ----

__global__ void k_cell(const float* __restrict__ anchors, int* __restrict__ cellid,
                       unsigned int* __restrict__ hist, int A) {
    int a = blockIdx.x * 256 + threadIdx.x;
    if (a >= A) return;
    float4 ab = ((const float4*)anchors)[a];
    float cx = (ab.x + ab.z) * 0.5f;   // precision irrelevant: binning only
    float cy = (ab.y + ab.w) * 0.5f;
    int cxi = (int)(cx * 0.02f); cxi = cxi < 0 ? 0 : (cxi > 15 ? 15 : cxi);
    int cyi = (int)(cy * 0.02f); cyi = cyi < 0 ? 0 : (cyi > 15 ? 15 : cyi);
    int c = cyi * 16 + cxi;
    cellid[a] = c;
    atomicAdd(&hist[c], 1u);
}

__global__ void k_scan(const unsigned int* __restrict__ hist,
                       unsigned int* __restrict__ offs) {
    __shared__ unsigned int s[NCELL];
    int t = threadIdx.x;
    unsigned int v = hist[t];
    s[t] = v;
    __syncthreads();
    for (int d = 1; d < NCELL; d <<= 1) {
        unsigned int add = (t >= d) ? s[t - d] : 0u;
        __syncthreads();
        s[t] += add;
        __syncthreads();
    }
    offs[t] = s[t] - v;   // exclusive prefix
}

__global__ void k_scatter(const int* __restrict__ cellid,
                          const unsigned int* __restrict__ offs,
                          unsigned int* __restrict__ cursor,
                          int* __restrict__ perm, int A) {
    int a = blockIdx.x * 256 + threadIdx.x;
    if (a >= A) return;
    int c = cellid[a];
    unsigned int pos = offs[c] + atomicAdd(&cursor[c], 1u);
    perm[pos] = a;
}

// ---- pass 1: highest_per_gt via per-lane m[64] + wave butterfly ----
// Block: 256 threads x 4 anchors = 1024 sorted-positions/block.
__global__ __launch_bounds__(256, 2)
void pass1_hpg(const float* __restrict__ gt,
               const float* __restrict__ anchors,
               const int* __restrict__ perm,
               unsigned int* __restrict__ hpg, int A) {
    const int b = blockIdx.y;
    const int t = threadIdx.x;

    __shared__ unsigned int sred[G];
    if (t < G) sred[t] = 0u;
    __syncthreads();

    const float4* gtb = (const float4*)(gt + (size_t)b * G * 4);

    float m[G];
#pragma unroll
    for (int g = 0; g < G; ++g) m[g] = 0.0f;

    const int base = blockIdx.x * 1024;
    for (int k = 0; k < 4; ++k) {
        int ap = base + k * 256 + t;
        bool v = (ap < A);
        int a = v ? (perm ? perm[ap] : ap) : 0;
        const float4 ab = ((const float4*)anchors)[a];
        float ax1 = v ? ab.x : -3.0e38f;
        float ay1 = v ? ab.y : -3.0e38f;
        float ax2 = v ? ab.z : -3.0e38f;
        float ay2 = v ? ab.w : -3.0e38f;
        float aar = box_area(ax1, ay1, ax2, ay2);   // 0 for degenerate

#pragma unroll
        for (int g = 0; g < G; ++g) {
            const float4 gb = gtb[g];               // uniform -> s_load
            float inter = inter_area(gb.x, gb.y, gb.z, gb.w, ax1, ay1, ax2, ay2);
            if (__ballot(inter > 0.0f)) {           // wave-uniform skip
                float ga = box_area(gb.x, gb.y, gb.z, gb.w);
                float q = iou_from_inter(inter, ga, aar);
                m[g] = fmaxf(m[g], q);              // inter==0 lanes: q==0, no-op
            }
        }
    }

    // one cross-lane butterfly for all 64 accumulators (max is associative)
#pragma unroll
    for (int st = 0; st < 6; ++st) {
#pragma unroll
        for (int g = 0; g < G; ++g)
            m[g] = fmaxf(m[g], __shfl_xor(m[g], 1 << st, 64));
    }

    if ((t & 63) == 0) {
#pragma unroll
        for (int g = 0; g < G; ++g)
            atomicMax(&sred[g], __float_as_uint(m[g]));
    }
    __syncthreads();
    if (t < G) atomicMax(&hpg[b * G + t], sred[t]);
}

// ---- pass 2: per anchor max/argmax/pu + thresholds, scatter via perm ----
// 256 threads x 2 anchors. Grid: (ceil(A/512), B).
__global__ __launch_bounds__(256, 8)
void pass2_match(const float* __restrict__ gt,
                 const float* __restrict__ anchors,
                 const int* __restrict__ perm,
                 const unsigned int* __restrict__ hpg,
                 float* __restrict__ out_idx,
                 float* __restrict__ out_val, int A) {
    const int b = blockIdx.y;
    const int t = threadIdx.x;

    const int base = blockIdx.x * 512;
    int aorig[2];
    float ax1[2], ay1[2], ax2[2], ay2[2], aar[2];
    bool val[2];
#pragma unroll
    for (int k = 0; k < 2; ++k) {
        int ap = base + k * 256 + t;
        val[k] = (ap < A);
        int a = val[k] ? (perm ? perm[ap] : ap) : 0;
        aorig[k] = a;
        const float4 ab = ((const float4*)anchors)[a];
        ax1[k] = val[k] ? ab.x : -3.0e38f;
        ay1[k] = val[k] ? ab.y : -3.0e38f;
        ax2[k] = val[k] ? ab.z : -3.0e38f;
        ay2[k] = val[k] ? ab.w : -3.0e38f;
        aar[k] = box_area(ax1[k], ay1[k], ax2[k], ay2[k]);
    }

    const float4* gtb = (const float4*)(gt + (size_t)b * G * 4);
    const unsigned int* hpgb = hpg + b * G;

    // init vmax=0/amax=0 replicates np.argmax over all-zero rows (first idx),
    // strict > update keeps the first max thereafter.
    float vmax[2] = {0.0f, 0.0f};
    int amax[2] = {0, 0};
    bool pu[2] = {false, false};
#pragma unroll 4
    for (int g = 0; g < G; ++g) {
        const float4 gb = gtb[g];                   // uniform -> s_load
        unsigned int hgu = hpgb[g];                 // uniform -> s_load
        float hg = __uint_as_float(hgu);
        float ga = box_area(gb.x, gb.y, gb.z, gb.w);
#pragma unroll
        for (int k = 0; k < 2; ++k) {
            float inter = inter_area(gb.x, gb.y, gb.z, gb.w,
                                     ax1[k], ay1[k], ax2[k], ay2[k]);
            if (__ballot(inter > 0.0f)) {           // wave-uniform skip
                float q = iou_from_inter(inter, ga, aar[k]);
                if (q > vmax[k]) { vmax[k] = q; amax[k] = g; }
                pu[k] = pu[k] || (q == hg);
            } else {
                // q == +0.0 exactly for every lane; q==hg  <=>  hg bits == 0
                pu[k] = pu[k] || (hgu == 0u);
            }
        }
    }

#pragma unroll
    for (int k = 0; k < 2; ++k) {
        if (!val[k]) continue;
        int m;
        if (pu[k]) {
            m = amax[k];                    // low-quality match recovery
        } else if (vmax[k] < 0.4f) {
            m = -1;                         // BELOW_LOW_QUALITY
        } else if (vmax[k] < 0.5f) {
            m = -2;                         // BETWEEN_THRESHOLDS
        } else {
            m = amax[k];
        }
        size_t o = (size_t)b * A + aorig[k];
        out_idx[o] = (float)m;
        out_val[o] = vmax[k];
    }
}

extern "C" void kernel_launch(void* const* d_in, const int* in_sizes, int n_in,
                              void* d_out, int out_size, void* d_ws, size_t ws_size,
                              hipStream_t stream) {
    const float* gt = (const float*)d_in[0];
    const float* anchors = (const float*)d_in[1];
    const int BG = in_sizes[0] / 4;   // B*G = 512
    const int B = BG / G;             // 8
    const int A = in_sizes[1] / 4;    // 120000

    // ws layout (u32 units):
    // [0,512) hpg | [512,768) hist | [768,1024) cursor | [1024,1280) offs
    // | [1280, 1280+A) cellid | [1280+A, 1280+2A) perm
    unsigned int* ws = (unsigned int*)d_ws;
    unsigned int* hpg = ws;
    unsigned int* hist = ws + 512;
    unsigned int* cursor = ws + 768;
    unsigned int* offs = ws + 1024;
    int* cellid = (int*)(ws + 1280);
    int* perm = cellid + A;
    const size_t need = (size_t)(1280 + 2 * (size_t)A) * 4;
    const bool use_sort = (ws_size >= need);

    float* out_idx = (float*)d_out;
    float* out_val = out_idx + (size_t)B * A;

    hipMemsetAsync(hpg, 0, 512 * 4, stream);               // hpg = 0 (+0.0f bits)
    const int* permp = nullptr;
    if (use_sort) {
        hipMemsetAsync(hist, 0, 512 * 4, stream);          // hist + cursor
        k_cell<<<(A + 255) / 256, 256, 0, stream>>>(anchors, cellid, hist, A);
        k_scan<<<1, NCELL, 0, stream>>>(hist, offs);
        k_scatter<<<(A + 255) / 256, 256, 0, stream>>>(cellid, offs, cursor, perm, A);
        permp = perm;
    }

    dim3 g1((A + 1023) / 1024, B);
    pass1_hpg<<<g1, 256, 0, stream>>>(gt, anchors, permp, hpg, A);

    dim3 g2((A + 511) / 512, B);
    pass2_match<<<g2, 256, 0, stream>>>(gt, anchors, permp, hpg, out_idx, out_val, A);
}

// Round 8
// 204.153 us; speedup vs baseline: 1.1730x; 1.1730x over previous
//
#include <hip/hip_runtime.h>

// RetinaNet matcher: gt_boxes [B=8, G=64, 4] f32, anchors [A=120000, 4] f32.
// Outputs (concat in d_out, f32): matched_idxs [B,A] (as float), matched_vals [B,A].
//
// Numerics (bit-exact vs np, verified R5/R6/R7 absmax 0.0): opaque() barriers
// on every mul result leave no legal FMA-contraction site -> every op is one
// deterministic IEEE instruction. argmax tie-break = first g (strict >).
// IoU >= 0 -> per-gt max reduces bit-exactly via uint atomicMax.
//
// R8: drop R7's sort/ballot (regression: branch bubbles + uncoalesced gather).
// Attack the measured ~74 VALU instrs/pair (vs ~25 ideal) directly:
//  - k_init precomputes ga[b,g] once (bit-identical box_area) -> both passes
//    s_load it; kills per-pair uniform recompute + SGPR-operand movs.
//  - pass1 re-partitioned: block = (b, g-octet, 2048 anchors); per-thread
//    m[8] accumulators (not m[64] -> no register starvation), 8 gt boxes
//    SGPR-resident, butterfly once at end, global atomicMax (no LDS/sync).
//    launch_bounds(256,8) -> 8 waves/SIMD for div-latency hiding.
//  - pass2: same as proven R6 shape minus ga recompute; pu via v_cmp_eq +
//    SALU s_or_b64 accumulation (off the VALU pipe).

static constexpr int G = 64;

__device__ __forceinline__ float opaque(float x) {
    asm volatile("" : "+v"(x));  // no-op; blocks FMA contraction across x
    return x;
}

__device__ __forceinline__ float box_area(float x1, float y1, float x2, float y2) {
    return opaque(__fmul_rn(__fsub_rn(x2, x1), __fsub_rn(y2, y1)));
}

__device__ __forceinline__ float inter_area(float gx1, float gy1, float gx2, float gy2,
                                            float ax1, float ay1, float ax2, float ay2) {
    float ltx = fmaxf(gx1, ax1);
    float lty = fmaxf(gy1, ay1);
    float rbx = fminf(gx2, ax2);
    float rby = fminf(gy2, ay2);
    float w = fmaxf(__fsub_rn(rbx, ltx), 0.0f);
    float h = fmaxf(__fsub_rn(rby, lty), 0.0f);
    return opaque(__fmul_rn(w, h));
}

// hpg[i] = 0 bits (+0.0f) and ga cache for all (b,g).
__global__ void k_init(const float* __restrict__ gt, unsigned int* __restrict__ hpg,
                       float* __restrict__ gab, int BG) {
    int i = blockIdx.x * 256 + threadIdx.x;
    if (i < BG) {
        hpg[i] = 0u;
        float4 gb = ((const float4*)gt)[i];
        gab[i] = box_area(gb.x, gb.y, gb.z, gb.w);
    }
}

// Pass 1: highest_per_gt. Block = 256 threads handling 8 gt (one octet) x
// 2048 anchors (8 per thread). Grid: (ceil(A/2048), G/8, B).
// Per-lane m[8]; one 6-stage butterfly at the end; 8 global atomics per wave.
__global__ __launch_bounds__(256, 8)
void pass1_hpg(const float* __restrict__ gt,
               const float* __restrict__ anchors,
               const float* __restrict__ gab,
               unsigned int* __restrict__ hpg, int A) {
    const int b = blockIdx.z;
    const int g0 = blockIdx.y * 8;
    const int t = threadIdx.x;

    const float4* gtb = (const float4*)gt + (size_t)b * G;
    const float* gas = gab + b * G;

    float gx1[8], gy1[8], gx2[8], gy2[8], ga[8];
#pragma unroll
    for (int j = 0; j < 8; ++j) {                 // uniform -> SGPR-resident
        float4 gb = gtb[g0 + j];
        gx1[j] = gb.x; gy1[j] = gb.y; gx2[j] = gb.z; gy2[j] = gb.w;
        ga[j] = gas[g0 + j];
    }

    float m[8];
#pragma unroll
    for (int j = 0; j < 8; ++j) m[j] = 0.0f;

    const int base = blockIdx.x * 2048;
#pragma unroll 1
    for (int k = 0; k < 8; ++k) {
        int a = base + k * 256 + t;
        bool v = (a < A);
        float4 ab = ((const float4*)anchors)[v ? a : 0];
        float ax1 = v ? ab.x : -3.0e38f;          // degenerate -> inter==+0, q==+0
        float ay1 = v ? ab.y : -3.0e38f;
        float ax2 = v ? ab.z : -3.0e38f;
        float ay2 = v ? ab.w : -3.0e38f;
        float aar = box_area(ax1, ay1, ax2, ay2);
#pragma unroll
        for (int j = 0; j < 8; ++j) {             // 8 independent div chains
            float inter = inter_area(gx1[j], gy1[j], gx2[j], gy2[j],
                                     ax1, ay1, ax2, ay2);
            float denom = __fsub_rn(__fadd_rn(ga[j], aar), inter);
            float q = __fdiv_rn(inter, denom);
            m[j] = fmaxf(m[j], q);
        }
    }

    // one cross-lane butterfly for the 8 accumulators (max is associative)
#pragma unroll
    for (int st = 0; st < 6; ++st) {
#pragma unroll
        for (int j = 0; j < 8; ++j)
            m[j] = fmaxf(m[j], __shfl_xor(m[j], 1 << st, 64));
    }

    if ((t & 63) == 0) {
#pragma unroll
        for (int j = 0; j < 8; ++j)
            atomicMax(&hpg[b * G + g0 + j], __float_as_uint(m[j]));
    }
}

// Pass 2: per anchor -> max/argmax over g, thresholds, low-quality recovery.
// gt/ga/hpg via uniform s_load; anchors per-lane. 2 anchors/thread.
// Grid: (ceil(A/512), B).
__global__ __launch_bounds__(256, 8)
void pass2_match(const float* __restrict__ gt,
                 const float* __restrict__ anchors,
                 const float* __restrict__ gab,
                 const unsigned int* __restrict__ hpg,
                 float* __restrict__ out_idx,
                 float* __restrict__ out_val, int A) {
    const int b = blockIdx.y;
    const int t = threadIdx.x;
    const int base = blockIdx.x * 512;

    float ax1[2], ay1[2], ax2[2], ay2[2], aar[2];
    bool val[2];
#pragma unroll
    for (int k = 0; k < 2; ++k) {
        int a = base + k * 256 + t;
        val[k] = (a < A);
        float4 ab = ((const float4*)anchors)[val[k] ? a : 0];
        ax1[k] = ab.x; ay1[k] = ab.y; ax2[k] = ab.z; ay2[k] = ab.w;
        aar[k] = box_area(ab.x, ab.y, ab.z, ab.w);
    }

    const float4* gtb = (const float4*)gt + (size_t)b * G;
    const float* gas = gab + b * G;
    const unsigned int* hpgb = hpg + b * G;

    // vmax=0/amax=0 start replicates np.argmax on an all-zero row (first idx);
    // strict > keeps the first max thereafter. q >= 0 always.
    float vmax[2] = {0.0f, 0.0f};
    int amax[2] = {0, 0};
    bool pu[2] = {false, false};
#pragma unroll 8
    for (int g = 0; g < G; ++g) {
        float4 gb = gtb[g];                        // uniform -> s_load
        float ga = gas[g];                         // uniform -> s_load
        float hg = __uint_as_float(hpgb[g]);       // uniform -> s_load
#pragma unroll
        for (int k = 0; k < 2; ++k) {
            float inter = inter_area(gb.x, gb.y, gb.z, gb.w,
                                     ax1[k], ay1[k], ax2[k], ay2[k]);
            float denom = __fsub_rn(__fadd_rn(ga, aar[k]), inter);
            float q = __fdiv_rn(inter, denom);
            pu[k] = pu[k] | (q == hg);
            if (q > vmax[k]) { vmax[k] = q; amax[k] = g; }  // first-max tie-break
        }
    }

#pragma unroll
    for (int k = 0; k < 2; ++k) {
        if (!val[k]) continue;
        int m;
        if (pu[k]) {
            m = amax[k];                    // low-quality match recovery
        } else if (vmax[k] < 0.4f) {
            m = -1;                         // BELOW_LOW_QUALITY
        } else if (vmax[k] < 0.5f) {
            m = -2;                         // BETWEEN_THRESHOLDS
        } else {
            m = amax[k];
        }
        size_t o = (size_t)b * A + (base + k * 256 + t);
        out_idx[o] = (float)m;
        out_val[o] = vmax[k];
    }
}

extern "C" void kernel_launch(void* const* d_in, const int* in_sizes, int n_in,
                              void* d_out, int out_size, void* d_ws, size_t ws_size,
                              hipStream_t stream) {
    const float* gt = (const float*)d_in[0];
    const float* anchors = (const float*)d_in[1];
    const int BG = in_sizes[0] / 4;   // B*G = 512
    const int B = BG / G;             // 8
    const int A = in_sizes[1] / 4;    // 120000

    // ws layout (u32 units): [0,512) hpg | [512,1024) ga cache
    unsigned int* hpg = (unsigned int*)d_ws;
    float* gab = (float*)d_ws + 512;

    float* out_idx = (float*)d_out;
    float* out_val = out_idx + (size_t)B * A;

    k_init<<<(BG + 255) / 256, 256, 0, stream>>>(gt, hpg, gab, BG);

    dim3 g1((A + 2047) / 2048, G / 8, B);
    pass1_hpg<<<g1, 256, 0, stream>>>(gt, anchors, gab, hpg, A);

    dim3 g2((A + 511) / 512, B);
    pass2_match<<<g2, 256, 0, stream>>>(gt, anchors, gab, hpg, out_idx, out_val, A);
}